// Round 17
// baseline (189.824 us; speedup 1.0000x reference)
//
#include <hip/hip_runtime.h>

#define TS 512  // timesteps
#define DD 64   // input dim
#define HH 32   // hidden dim

#define LOG2E 1.4426950408889634f

typedef _Float16 half2v __attribute__((ext_vector_type(2)));

__device__ __forceinline__ float fdot2(half2v a, half2v b, float c) {
#if __has_builtin(__builtin_amdgcn_fdot2)
    return __builtin_amdgcn_fdot2(a, b, c, false);
#else
    return fmaf((float)a[0], (float)b[0], fmaf((float)a[1], (float)b[1], c));
#endif
}

__device__ __forceinline__ float fexp2(float x) {
#if __has_builtin(__builtin_amdgcn_exp2f)
    return __builtin_amdgcn_exp2f(x);
#else
    return exp2f(x);
#endif
}

__device__ __forceinline__ half2v h2(unsigned int u) {
    return __builtin_bit_cast(half2v, u);
}

// One wave (64 lanes) per batch element.  lane = s*32 + h.
// Round-16 source (171.4us best) with ONE control-flow change: the
// `if (t+1 < TS)` guard around the xg cover block is removed by running
// the loop to TS-1 and peeling the final iteration (which needs no xg,
// no staging, no h broadcast). The per-iter compare+cbranch fenced the
// scheduler in the cover region; unconditional code lets it hoist/merge
// ds_reads and waitcnts. Arithmetic bit-identical to round 16.
__global__ __launch_bounds__(64)
__attribute__((amdgpu_waves_per_eu(1, 1)))
void gru_fused(
    const float* __restrict__ x,
    const float* __restrict__ Wih,
    const float* __restrict__ Whh,
    const float* __restrict__ bih,
    const float* __restrict__ bhh,
    const float* __restrict__ Wfc,
    const float* __restrict__ bfc,
    float* __restrict__ out)
{
    __shared__ __align__(16) _Float16 xs16[4][DD];  // rotating x staging (fp16)
    __shared__ __align__(16) _Float16 hs16[HH];     // h broadcast (fp16)
    __shared__ __align__(16) float    ps[2][HH][4]; // partial exchange (f32x4)

    const int b    = blockIdx.x;
    const int lane = threadIdx.x;
    const int s    = lane >> 5;   // 0/1: which half of the dot
    const int h    = lane & 31;   // hidden index owned by this lane

    // ---- W_ih rows (r,z,n), this lane's d-half: 48 packed regs (scaled) ----
    half2v wr2[16], wz2[16], wn2[16];
    {
        const float4* pr = reinterpret_cast<const float4*>(Wih + (0 * HH + h) * DD + s * 32);
        const float4* pz = reinterpret_cast<const float4*>(Wih + (1 * HH + h) * DD + s * 32);
        const float4* pn = reinterpret_cast<const float4*>(Wih + (2 * HH + h) * DD + s * 32);
#pragma unroll
        for (int k = 0; k < 8; ++k) {
            float4 a = pr[k];
            wr2[2*k]   = half2v{(_Float16)(a.x * LOG2E), (_Float16)(a.y * LOG2E)};
            wr2[2*k+1] = half2v{(_Float16)(a.z * LOG2E), (_Float16)(a.w * LOG2E)};
            float4 c = pz[k];
            wz2[2*k]   = half2v{(_Float16)(c.x * LOG2E), (_Float16)(c.y * LOG2E)};
            wz2[2*k+1] = half2v{(_Float16)(c.z * LOG2E), (_Float16)(c.w * LOG2E)};
            float4 e = pn[k];
            wn2[2*k]   = half2v{(_Float16)(e.x * 2.0f * LOG2E), (_Float16)(e.y * 2.0f * LOG2E)};
            wn2[2*k+1] = half2v{(_Float16)(e.z * 2.0f * LOG2E), (_Float16)(e.w * 2.0f * LOG2E)};
        }
    }
    // ---- W_hh rows, this lane's j-half: 24 packed regs (scaled) ----
    half2v ur2[8], uz2[8], un2[8];
    {
        const float4* pr = reinterpret_cast<const float4*>(Whh + (0 * HH + h) * HH + s * 16);
        const float4* pz = reinterpret_cast<const float4*>(Whh + (1 * HH + h) * HH + s * 16);
        const float4* pn = reinterpret_cast<const float4*>(Whh + (2 * HH + h) * HH + s * 16);
#pragma unroll
        for (int k = 0; k < 4; ++k) {
            float4 a = pr[k];
            ur2[2*k]   = half2v{(_Float16)(a.x * LOG2E), (_Float16)(a.y * LOG2E)};
            ur2[2*k+1] = half2v{(_Float16)(a.z * LOG2E), (_Float16)(a.w * LOG2E)};
            float4 c = pz[k];
            uz2[2*k]   = half2v{(_Float16)(c.x * LOG2E), (_Float16)(c.y * LOG2E)};
            uz2[2*k+1] = half2v{(_Float16)(c.z * LOG2E), (_Float16)(c.w * LOG2E)};
            float4 e = pn[k];
            un2[2*k]   = half2v{(_Float16)(e.x * 2.0f * LOG2E), (_Float16)(e.y * 2.0f * LOG2E)};
            un2[2*k+1] = half2v{(_Float16)(e.z * 2.0f * LOG2E), (_Float16)(e.w * 2.0f * LOG2E)};
        }
    }

    const float br  = (bih[h]          + bhh[h])      * LOG2E;
    const float bz  = (bih[HH + h]     + bhh[HH + h]) * LOG2E;
    const float bxn = bih[2 * HH + h] * 2.0f * LOG2E;
    const float bhn = bhh[2 * HH + h] * 2.0f * LOG2E;
    const float wfc = Wfc[h];
    const float bf0 = bfc[0];

    const float* xrow = x + (size_t)b * TS * DD;

    // ---- prologue: stage slots 0..2, keep 3 loads in flight ----
    float p0 = xrow[0 * DD + lane];
    float p1 = xrow[1 * DD + lane];
    float p2 = xrow[2 * DD + lane];
    float ra = xrow[3 * DD + lane];
    float rb = xrow[4 * DD + lane];
    float rc = xrow[5 * DD + lane];
    xs16[0][lane] = (_Float16)p0;
    xs16[1][lane] = (_Float16)p1;
    xs16[2][lane] = (_Float16)p2;
    __builtin_amdgcn_wave_barrier();

    float h_own = 0.0f;
    half2v hv2[8];
#pragma unroll
    for (int k = 0; k < 8; ++k) hv2[k] = half2v{(_Float16)0.0f, (_Float16)0.0f};

    // xg partials for t=0 (x already staged)
    float ar, az, an;
    {
        const uint4* xp = reinterpret_cast<const uint4*>(&xs16[0][s * 32]);
        ar = 0.f; az = 0.f; an = 0.f;
#pragma unroll
        for (int k = 0; k < 4; ++k) {
            uint4 q = xp[k];
            half2v v0 = h2(q.x), v1 = h2(q.y), v2 = h2(q.z), v3 = h2(q.w);
            ar = fdot2(wr2[4*k  ], v0, ar);
            az = fdot2(wz2[4*k  ], v0, az);
            an = fdot2(wn2[4*k  ], v0, an);
            ar = fdot2(wr2[4*k+1], v1, ar);
            az = fdot2(wz2[4*k+1], v1, az);
            an = fdot2(wn2[4*k+1], v1, an);
            ar = fdot2(wr2[4*k+2], v2, ar);
            az = fdot2(wz2[4*k+2], v2, az);
            an = fdot2(wn2[4*k+2], v2, an);
            ar = fdot2(wr2[4*k+3], v3, ar);
            az = fdot2(wz2[4*k+3], v3, az);
            an = fdot2(wn2[4*k+3], v3, an);
        }
    }

    for (int t = 0; t < TS - 1; ++t) {
        // ---- gh partial dots (this lane's 16 of 32 j's) ----
        float gr = 0.f, gz = 0.f, gn = 0.f;
#pragma unroll
        for (int k = 0; k < 8; ++k) {
            gr = fdot2(ur2[k], hv2[k], gr);
            gz = fdot2(uz2[k], hv2[k], gz);
            gn = fdot2(un2[k], hv2[k], gn);
        }

        // ---- write my partials (one b128); partner read comes later ----
        float4 mypart;
        mypart.x = ar + gr;
        mypart.y = az + gz;
        mypart.z = an;
        mypart.w = gn;
        *reinterpret_cast<float4*>(&ps[s][h][0]) = mypart;
        __builtin_amdgcn_wave_barrier();

        // ---- staging for step t+3 (fills part of the round trip) ----
        xs16[(t + 3) & 3][lane] = (_Float16)ra;
        ra = rb; rb = rc;
        int tf = t + 6; if (tf > TS - 1) tf = TS - 1;   // harmless tail re-read
        rc = xrow[tf * DD + lane];

        // ---- xg partials for step t+1 (UNCONDITIONAL; covers ps trip) ----
        {
            const uint4* xp = reinterpret_cast<const uint4*>(&xs16[(t + 1) & 3][s * 32]);
            ar = 0.f; az = 0.f; an = 0.f;
#pragma unroll
            for (int k = 0; k < 4; ++k) {
                uint4 q = xp[k];
                half2v v0 = h2(q.x), v1 = h2(q.y), v2 = h2(q.z), v3 = h2(q.w);
                ar = fdot2(wr2[4*k  ], v0, ar);
                az = fdot2(wz2[4*k  ], v0, az);
                an = fdot2(wn2[4*k  ], v0, an);
                ar = fdot2(wr2[4*k+1], v1, ar);
                az = fdot2(wz2[4*k+1], v1, az);
                an = fdot2(wn2[4*k+1], v1, an);
                ar = fdot2(wr2[4*k+2], v2, ar);
                az = fdot2(wz2[4*k+2], v2, az);
                an = fdot2(wn2[4*k+2], v2, an);
                ar = fdot2(wr2[4*k+3], v3, ar);
                az = fdot2(wz2[4*k+3], v3, az);
                an = fdot2(wn2[4*k+3], v3, an);
            }
        }

        // ---- read partner partials and combine ----
        __builtin_amdgcn_wave_barrier();
        float4 other = *reinterpret_cast<const float4*>(&ps[s ^ 1][h][0]);
        float tr  = mypart.x + other.x;
        float tz  = mypart.y + other.y;
        float txn = mypart.z + other.z;
        float tgn = mypart.w + other.w;

        // ---- gates: exp2-direct (log2e pre-folded into weights) ----
        float r = __builtin_amdgcn_rcpf(1.0f + fexp2(-(tr + br)));
        float z = __builtin_amdgcn_rcpf(1.0f + fexp2(-(tz + bz)));
        float npre2 = txn + bxn + r * (tgn + bhn);
        npre2 = fmaxf(npre2, -60.f);
        float e2 = fexp2(-npre2);
        float n = (1.f - e2) * __builtin_amdgcn_rcpf(1.f + e2);
        h_own = n + z * (h_own - n);

        // ---- broadcast h (fp16) — wave-synchronous, block == 1 wave ----
        hs16[h] = (_Float16)h_own;
        __builtin_amdgcn_wave_barrier();
        {
            const uint4* hp = reinterpret_cast<const uint4*>(&hs16[s * 16]);
            uint4 q0 = hp[0];
            uint4 q1 = hp[1];
            hv2[0] = h2(q0.x);
            hv2[1] = h2(q0.y);
            hv2[2] = h2(q0.z);
            hv2[3] = h2(q0.w);
            hv2[4] = h2(q1.x);
            hv2[5] = h2(q1.y);
            hv2[6] = h2(q1.z);
            hv2[7] = h2(q1.w);
        }
    }

    // ---- peeled final iteration (t = TS-1): no xg, no staging, no bcast ----
    {
        float gr = 0.f, gz = 0.f, gn = 0.f;
#pragma unroll
        for (int k = 0; k < 8; ++k) {
            gr = fdot2(ur2[k], hv2[k], gr);
            gz = fdot2(uz2[k], hv2[k], gz);
            gn = fdot2(un2[k], hv2[k], gn);
        }
        float4 mypart;
        mypart.x = ar + gr;
        mypart.y = az + gz;
        mypart.z = an;
        mypart.w = gn;
        *reinterpret_cast<float4*>(&ps[s][h][0]) = mypart;
        __builtin_amdgcn_wave_barrier();
        float4 other = *reinterpret_cast<const float4*>(&ps[s ^ 1][h][0]);
        float tr  = mypart.x + other.x;
        float tz  = mypart.y + other.y;
        float txn = mypart.z + other.z;
        float tgn = mypart.w + other.w;

        float r = __builtin_amdgcn_rcpf(1.0f + fexp2(-(tr + br)));
        float z = __builtin_amdgcn_rcpf(1.0f + fexp2(-(tz + bz)));
        float npre2 = txn + bxn + r * (tgn + bhn);
        npre2 = fmaxf(npre2, -60.f);
        float e2 = fexp2(-npre2);
        float n = (1.f - e2) * __builtin_amdgcn_rcpf(1.f + e2);
        h_own = n + z * (h_own - n);
    }

    // ---- final fc: out[b] = dot(h, W_fc) + b_fc (each h counted twice) ----
    float v = h_own * wfc;
#pragma unroll
    for (int off = 32; off >= 1; off >>= 1) v += __shfl_xor(v, off);
    if (lane == 0) out[b] = 0.5f * v + bf0;
}

extern "C" void kernel_launch(void* const* d_in, const int* in_sizes, int n_in,
                              void* d_out, int out_size, void* d_ws, size_t ws_size,
                              hipStream_t stream) {
    const float* x    = (const float*)d_in[0];
    const float* Wih  = (const float*)d_in[1];
    const float* Whh  = (const float*)d_in[2];
    const float* bih  = (const float*)d_in[3];
    const float* bhh  = (const float*)d_in[4];
    const float* Wfc  = (const float*)d_in[5];
    const float* bfc  = (const float*)d_in[6];
    float* out = (float*)d_out;

    const int B = in_sizes[0] / (TS * DD);   // 1024
    gru_fused<<<dim3(B), dim3(64), 0, stream>>>(x, Wih, Whh, bih, bhh, Wfc, bfc, out);
}

// Round 18
// 172.286 us; speedup vs baseline: 1.1018x; 1.1018x over previous
//
#include <hip/hip_runtime.h>

#define TS 512  // timesteps
#define DD 64   // input dim
#define HH 32   // hidden dim

#define LOG2E 1.4426950408889634f

typedef _Float16 half2v __attribute__((ext_vector_type(2)));

__device__ __forceinline__ float fdot2(half2v a, half2v b, float c) {
#if __has_builtin(__builtin_amdgcn_fdot2)
    return __builtin_amdgcn_fdot2(a, b, c, false);
#else
    return fmaf((float)a[0], (float)b[0], fmaf((float)a[1], (float)b[1], c));
#endif
}

__device__ __forceinline__ float fexp2(float x) {
#if __has_builtin(__builtin_amdgcn_exp2f)
    return __builtin_amdgcn_exp2f(x);
#else
    return exp2f(x);
#endif
}

__device__ __forceinline__ half2v h2(unsigned int u) {
    return __builtin_bit_cast(half2v, u);
}

// One wave (64 lanes) per batch element.  lane = s*32 + h.
// EXACT round-16 source (best measured: 171.4us, absmax 0.0078125).
// Structure: half-split dots (r10) + LDS partial-exchange hidden under
// the t+1 xg block (r13) + log2e folded into weights (r16).
// Reverted here after r14/r15/r17 scheduling variants all regressed
// (192.8 / 237.2 / 189.8) — this compile is the scheduling optimum.
__global__ __launch_bounds__(64)
__attribute__((amdgpu_waves_per_eu(1, 1)))
void gru_fused(
    const float* __restrict__ x,
    const float* __restrict__ Wih,
    const float* __restrict__ Whh,
    const float* __restrict__ bih,
    const float* __restrict__ bhh,
    const float* __restrict__ Wfc,
    const float* __restrict__ bfc,
    float* __restrict__ out)
{
    __shared__ __align__(16) _Float16 xs16[4][DD];  // rotating x staging (fp16)
    __shared__ __align__(16) _Float16 hs16[HH];     // h broadcast (fp16)
    __shared__ __align__(16) float    ps[2][HH][4]; // partial exchange (f32x4)

    const int b    = blockIdx.x;
    const int lane = threadIdx.x;
    const int s    = lane >> 5;   // 0/1: which half of the dot
    const int h    = lane & 31;   // hidden index owned by this lane

    // ---- W_ih rows (r,z,n), this lane's d-half: 48 packed regs (scaled) ----
    half2v wr2[16], wz2[16], wn2[16];
    {
        const float4* pr = reinterpret_cast<const float4*>(Wih + (0 * HH + h) * DD + s * 32);
        const float4* pz = reinterpret_cast<const float4*>(Wih + (1 * HH + h) * DD + s * 32);
        const float4* pn = reinterpret_cast<const float4*>(Wih + (2 * HH + h) * DD + s * 32);
#pragma unroll
        for (int k = 0; k < 8; ++k) {
            float4 a = pr[k];
            wr2[2*k]   = half2v{(_Float16)(a.x * LOG2E), (_Float16)(a.y * LOG2E)};
            wr2[2*k+1] = half2v{(_Float16)(a.z * LOG2E), (_Float16)(a.w * LOG2E)};
            float4 c = pz[k];
            wz2[2*k]   = half2v{(_Float16)(c.x * LOG2E), (_Float16)(c.y * LOG2E)};
            wz2[2*k+1] = half2v{(_Float16)(c.z * LOG2E), (_Float16)(c.w * LOG2E)};
            float4 e = pn[k];
            wn2[2*k]   = half2v{(_Float16)(e.x * 2.0f * LOG2E), (_Float16)(e.y * 2.0f * LOG2E)};
            wn2[2*k+1] = half2v{(_Float16)(e.z * 2.0f * LOG2E), (_Float16)(e.w * 2.0f * LOG2E)};
        }
    }
    // ---- W_hh rows, this lane's j-half: 24 packed regs (scaled) ----
    half2v ur2[8], uz2[8], un2[8];
    {
        const float4* pr = reinterpret_cast<const float4*>(Whh + (0 * HH + h) * HH + s * 16);
        const float4* pz = reinterpret_cast<const float4*>(Whh + (1 * HH + h) * HH + s * 16);
        const float4* pn = reinterpret_cast<const float4*>(Whh + (2 * HH + h) * HH + s * 16);
#pragma unroll
        for (int k = 0; k < 4; ++k) {
            float4 a = pr[k];
            ur2[2*k]   = half2v{(_Float16)(a.x * LOG2E), (_Float16)(a.y * LOG2E)};
            ur2[2*k+1] = half2v{(_Float16)(a.z * LOG2E), (_Float16)(a.w * LOG2E)};
            float4 c = pz[k];
            uz2[2*k]   = half2v{(_Float16)(c.x * LOG2E), (_Float16)(c.y * LOG2E)};
            uz2[2*k+1] = half2v{(_Float16)(c.z * LOG2E), (_Float16)(c.w * LOG2E)};
            float4 e = pn[k];
            un2[2*k]   = half2v{(_Float16)(e.x * 2.0f * LOG2E), (_Float16)(e.y * 2.0f * LOG2E)};
            un2[2*k+1] = half2v{(_Float16)(e.z * 2.0f * LOG2E), (_Float16)(e.w * 2.0f * LOG2E)};
        }
    }

    const float br  = (bih[h]          + bhh[h])      * LOG2E;
    const float bz  = (bih[HH + h]     + bhh[HH + h]) * LOG2E;
    const float bxn = bih[2 * HH + h] * 2.0f * LOG2E;
    const float bhn = bhh[2 * HH + h] * 2.0f * LOG2E;
    const float wfc = Wfc[h];
    const float bf0 = bfc[0];

    const float* xrow = x + (size_t)b * TS * DD;

    // ---- prologue: stage slots 0..2, keep 3 loads in flight ----
    float p0 = xrow[0 * DD + lane];
    float p1 = xrow[1 * DD + lane];
    float p2 = xrow[2 * DD + lane];
    float ra = xrow[3 * DD + lane];
    float rb = xrow[4 * DD + lane];
    float rc = xrow[5 * DD + lane];
    xs16[0][lane] = (_Float16)p0;
    xs16[1][lane] = (_Float16)p1;
    xs16[2][lane] = (_Float16)p2;
    __builtin_amdgcn_wave_barrier();

    float h_own = 0.0f;
    half2v hv2[8];
#pragma unroll
    for (int k = 0; k < 8; ++k) hv2[k] = half2v{(_Float16)0.0f, (_Float16)0.0f};

    // xg partials for t=0 (x already staged)
    float ar, az, an;
    {
        const uint4* xp = reinterpret_cast<const uint4*>(&xs16[0][s * 32]);
        ar = 0.f; az = 0.f; an = 0.f;
#pragma unroll
        for (int k = 0; k < 4; ++k) {
            uint4 q = xp[k];
            half2v v0 = h2(q.x), v1 = h2(q.y), v2 = h2(q.z), v3 = h2(q.w);
            ar = fdot2(wr2[4*k  ], v0, ar);
            az = fdot2(wz2[4*k  ], v0, az);
            an = fdot2(wn2[4*k  ], v0, an);
            ar = fdot2(wr2[4*k+1], v1, ar);
            az = fdot2(wz2[4*k+1], v1, az);
            an = fdot2(wn2[4*k+1], v1, an);
            ar = fdot2(wr2[4*k+2], v2, ar);
            az = fdot2(wz2[4*k+2], v2, az);
            an = fdot2(wn2[4*k+2], v2, an);
            ar = fdot2(wr2[4*k+3], v3, ar);
            az = fdot2(wz2[4*k+3], v3, az);
            an = fdot2(wn2[4*k+3], v3, an);
        }
    }

    for (int t = 0; t < TS; ++t) {
        // ---- gh partial dots (this lane's 16 of 32 j's) ----
        float gr = 0.f, gz = 0.f, gn = 0.f;
#pragma unroll
        for (int k = 0; k < 8; ++k) {
            gr = fdot2(ur2[k], hv2[k], gr);
            gz = fdot2(uz2[k], hv2[k], gz);
            gn = fdot2(un2[k], hv2[k], gn);
        }

        // ---- write my partials (one b128); partner read comes later ----
        float4 mypart;
        mypart.x = ar + gr;
        mypart.y = az + gz;
        mypart.z = an;
        mypart.w = gn;
        *reinterpret_cast<float4*>(&ps[s][h][0]) = mypart;
        __builtin_amdgcn_wave_barrier();

        // ---- staging for step t+3 (fills part of the round trip) ----
        xs16[(t + 3) & 3][lane] = (_Float16)ra;
        ra = rb; rb = rc;
        int tf = t + 6; if (tf > TS - 1) tf = TS - 1;   // harmless tail re-read
        rc = xrow[tf * DD + lane];

        // ---- xg partials for step t+1 (covers the partial round trip) ----
        if (t + 1 < TS) {
            const uint4* xp = reinterpret_cast<const uint4*>(&xs16[(t + 1) & 3][s * 32]);
            ar = 0.f; az = 0.f; an = 0.f;
#pragma unroll
            for (int k = 0; k < 4; ++k) {
                uint4 q = xp[k];
                half2v v0 = h2(q.x), v1 = h2(q.y), v2 = h2(q.z), v3 = h2(q.w);
                ar = fdot2(wr2[4*k  ], v0, ar);
                az = fdot2(wz2[4*k  ], v0, az);
                an = fdot2(wn2[4*k  ], v0, an);
                ar = fdot2(wr2[4*k+1], v1, ar);
                az = fdot2(wz2[4*k+1], v1, az);
                an = fdot2(wn2[4*k+1], v1, an);
                ar = fdot2(wr2[4*k+2], v2, ar);
                az = fdot2(wz2[4*k+2], v2, az);
                an = fdot2(wn2[4*k+2], v2, an);
                ar = fdot2(wr2[4*k+3], v3, ar);
                az = fdot2(wz2[4*k+3], v3, az);
                an = fdot2(wn2[4*k+3], v3, an);
            }
        }

        // ---- read partner partials and combine ----
        __builtin_amdgcn_wave_barrier();
        float4 other = *reinterpret_cast<const float4*>(&ps[s ^ 1][h][0]);
        float tr  = mypart.x + other.x;   // scaled by log2e
        float tz  = mypart.y + other.y;   // scaled by log2e
        float txn = mypart.z + other.z;   // scaled by 2*log2e
        float tgn = mypart.w + other.w;   // scaled by 2*log2e

        // ---- gates: exp2-direct (log2e pre-folded into weights) ----
        float r = __builtin_amdgcn_rcpf(1.0f + fexp2(-(tr + br)));
        float z = __builtin_amdgcn_rcpf(1.0f + fexp2(-(tz + bz)));
        float npre2 = txn + bxn + r * (tgn + bhn);   // = 2*log2e*npre
        npre2 = fmaxf(npre2, -60.f);                 // only -inf side can NaN
        float e2 = fexp2(-npre2);
        float n = (1.f - e2) * __builtin_amdgcn_rcpf(1.f + e2);
        h_own = n + z * (h_own - n);

        // ---- broadcast h (fp16) — wave-synchronous, block == 1 wave ----
        hs16[h] = (_Float16)h_own;
        __builtin_amdgcn_wave_barrier();
        {
            const uint4* hp = reinterpret_cast<const uint4*>(&hs16[s * 16]);
            uint4 q0 = hp[0];
            uint4 q1 = hp[1];
            hv2[0] = h2(q0.x);
            hv2[1] = h2(q0.y);
            hv2[2] = h2(q0.z);
            hv2[3] = h2(q0.w);
            hv2[4] = h2(q1.x);
            hv2[5] = h2(q1.y);
            hv2[6] = h2(q1.z);
            hv2[7] = h2(q1.w);
        }
    }

    // ---- final fc: out[b] = dot(h, W_fc) + b_fc (each h counted twice) ----
    float v = h_own * wfc;
#pragma unroll
    for (int off = 32; off >= 1; off >>= 1) v += __shfl_xor(v, off);
    if (lane == 0) out[b] = 0.5f * v + bf0;
}

extern "C" void kernel_launch(void* const* d_in, const int* in_sizes, int n_in,
                              void* d_out, int out_size, void* d_ws, size_t ws_size,
                              hipStream_t stream) {
    const float* x    = (const float*)d_in[0];
    const float* Wih  = (const float*)d_in[1];
    const float* Whh  = (const float*)d_in[2];
    const float* bih  = (const float*)d_in[3];
    const float* bhh  = (const float*)d_in[4];
    const float* Wfc  = (const float*)d_in[5];
    const float* bfc  = (const float*)d_in[6];
    float* out = (float*)d_out;

    const int B = in_sizes[0] / (TS * DD);   // 1024
    gru_fused<<<dim3(B), dim3(64), 0, stream>>>(x, Wih, Whh, bih, bhh, Wfc, bfc, out);
}

// Round 19
// 166.173 us; speedup vs baseline: 1.1423x; 1.0368x over previous
//
#include <hip/hip_runtime.h>

#define TS 512  // timesteps
#define DD 64   // input dim
#define HH 32   // hidden dim

#define LOG2E 1.4426950408889634f

typedef _Float16 half2v __attribute__((ext_vector_type(2)));

__device__ __forceinline__ float fdot2(half2v a, half2v b, float c) {
#if __has_builtin(__builtin_amdgcn_fdot2)
    return __builtin_amdgcn_fdot2(a, b, c, false);
#else
    return fmaf((float)a[0], (float)b[0], fmaf((float)a[1], (float)b[1], c));
#endif
}

__device__ __forceinline__ float fexp2(float x) {
#if __has_builtin(__builtin_amdgcn_exp2f)
    return __builtin_amdgcn_exp2f(x);
#else
    return exp2f(x);
#endif
}

__device__ __forceinline__ half2v h2(unsigned int u) {
    return __builtin_bit_cast(half2v, u);
}

// One wave (64 lanes) per batch element.  lane = s*32 + h.
// Round-16 source (171.4us best) with ONE change: the 4 ds_read_b128
// of x[t+1] are HOISTED from the cover block to the iteration top, so
// (a) their latency overlaps the gh dots (which depend only on hv2),
// and (b) the ps partial-exchange read no longer queues behind them
// (DS returns are in-order — r14 finding). The cover block between
// ps write and ps read becomes staging + pure-VALU fdot2 on pre-read
// registers. Arithmetic value-identical to round 16.
__global__ __launch_bounds__(64)
__attribute__((amdgpu_waves_per_eu(1, 1)))
void gru_fused(
    const float* __restrict__ x,
    const float* __restrict__ Wih,
    const float* __restrict__ Whh,
    const float* __restrict__ bih,
    const float* __restrict__ bhh,
    const float* __restrict__ Wfc,
    const float* __restrict__ bfc,
    float* __restrict__ out)
{
    __shared__ __align__(16) _Float16 xs16[4][DD];  // rotating x staging (fp16)
    __shared__ __align__(16) _Float16 hs16[HH];     // h broadcast (fp16)
    __shared__ __align__(16) float    ps[2][HH][4]; // partial exchange (f32x4)

    const int b    = blockIdx.x;
    const int lane = threadIdx.x;
    const int s    = lane >> 5;   // 0/1: which half of the dot
    const int h    = lane & 31;   // hidden index owned by this lane

    // ---- W_ih rows (r,z,n), this lane's d-half: 48 packed regs (scaled) ----
    half2v wr2[16], wz2[16], wn2[16];
    {
        const float4* pr = reinterpret_cast<const float4*>(Wih + (0 * HH + h) * DD + s * 32);
        const float4* pz = reinterpret_cast<const float4*>(Wih + (1 * HH + h) * DD + s * 32);
        const float4* pn = reinterpret_cast<const float4*>(Wih + (2 * HH + h) * DD + s * 32);
#pragma unroll
        for (int k = 0; k < 8; ++k) {
            float4 a = pr[k];
            wr2[2*k]   = half2v{(_Float16)(a.x * LOG2E), (_Float16)(a.y * LOG2E)};
            wr2[2*k+1] = half2v{(_Float16)(a.z * LOG2E), (_Float16)(a.w * LOG2E)};
            float4 c = pz[k];
            wz2[2*k]   = half2v{(_Float16)(c.x * LOG2E), (_Float16)(c.y * LOG2E)};
            wz2[2*k+1] = half2v{(_Float16)(c.z * LOG2E), (_Float16)(c.w * LOG2E)};
            float4 e = pn[k];
            wn2[2*k]   = half2v{(_Float16)(e.x * 2.0f * LOG2E), (_Float16)(e.y * 2.0f * LOG2E)};
            wn2[2*k+1] = half2v{(_Float16)(e.z * 2.0f * LOG2E), (_Float16)(e.w * 2.0f * LOG2E)};
        }
    }
    // ---- W_hh rows, this lane's j-half: 24 packed regs (scaled) ----
    half2v ur2[8], uz2[8], un2[8];
    {
        const float4* pr = reinterpret_cast<const float4*>(Whh + (0 * HH + h) * HH + s * 16);
        const float4* pz = reinterpret_cast<const float4*>(Whh + (1 * HH + h) * HH + s * 16);
        const float4* pn = reinterpret_cast<const float4*>(Whh + (2 * HH + h) * HH + s * 16);
#pragma unroll
        for (int k = 0; k < 4; ++k) {
            float4 a = pr[k];
            ur2[2*k]   = half2v{(_Float16)(a.x * LOG2E), (_Float16)(a.y * LOG2E)};
            ur2[2*k+1] = half2v{(_Float16)(a.z * LOG2E), (_Float16)(a.w * LOG2E)};
            float4 c = pz[k];
            uz2[2*k]   = half2v{(_Float16)(c.x * LOG2E), (_Float16)(c.y * LOG2E)};
            uz2[2*k+1] = half2v{(_Float16)(c.z * LOG2E), (_Float16)(c.w * LOG2E)};
            float4 e = pn[k];
            un2[2*k]   = half2v{(_Float16)(e.x * 2.0f * LOG2E), (_Float16)(e.y * 2.0f * LOG2E)};
            un2[2*k+1] = half2v{(_Float16)(e.z * 2.0f * LOG2E), (_Float16)(e.w * 2.0f * LOG2E)};
        }
    }

    const float br  = (bih[h]          + bhh[h])      * LOG2E;
    const float bz  = (bih[HH + h]     + bhh[HH + h]) * LOG2E;
    const float bxn = bih[2 * HH + h] * 2.0f * LOG2E;
    const float bhn = bhh[2 * HH + h] * 2.0f * LOG2E;
    const float wfc = Wfc[h];
    const float bf0 = bfc[0];

    const float* xrow = x + (size_t)b * TS * DD;

    // ---- prologue: stage slots 0..2, keep 3 loads in flight ----
    float p0 = xrow[0 * DD + lane];
    float p1 = xrow[1 * DD + lane];
    float p2 = xrow[2 * DD + lane];
    float ra = xrow[3 * DD + lane];
    float rb = xrow[4 * DD + lane];
    float rc = xrow[5 * DD + lane];
    xs16[0][lane] = (_Float16)p0;
    xs16[1][lane] = (_Float16)p1;
    xs16[2][lane] = (_Float16)p2;
    __builtin_amdgcn_wave_barrier();

    float h_own = 0.0f;
    half2v hv2[8];
#pragma unroll
    for (int k = 0; k < 8; ++k) hv2[k] = half2v{(_Float16)0.0f, (_Float16)0.0f};

    // xg partials for t=0 (x already staged)
    float ar, az, an;
    {
        const uint4* xp = reinterpret_cast<const uint4*>(&xs16[0][s * 32]);
        ar = 0.f; az = 0.f; an = 0.f;
#pragma unroll
        for (int k = 0; k < 4; ++k) {
            uint4 q = xp[k];
            half2v v0 = h2(q.x), v1 = h2(q.y), v2 = h2(q.z), v3 = h2(q.w);
            ar = fdot2(wr2[4*k  ], v0, ar);
            az = fdot2(wz2[4*k  ], v0, az);
            an = fdot2(wn2[4*k  ], v0, an);
            ar = fdot2(wr2[4*k+1], v1, ar);
            az = fdot2(wz2[4*k+1], v1, az);
            an = fdot2(wn2[4*k+1], v1, an);
            ar = fdot2(wr2[4*k+2], v2, ar);
            az = fdot2(wz2[4*k+2], v2, az);
            an = fdot2(wn2[4*k+2], v2, an);
            ar = fdot2(wr2[4*k+3], v3, ar);
            az = fdot2(wz2[4*k+3], v3, az);
            an = fdot2(wn2[4*k+3], v3, an);
        }
    }

    for (int t = 0; t < TS; ++t) {
        // ---- HOISTED: pre-read x[t+1] (4x ds_read_b128); latency overlaps
        //      the gh dots below, and the ps read no longer queues behind
        //      these (in-order DS returns). Slot (t+1)&3 was written at
        //      iter t-2 -> safe. At t=TS-1 reads stale slot 0 (unused).
        uint4 xq0, xq1, xq2, xq3;
        {
            const uint4* xp = reinterpret_cast<const uint4*>(&xs16[(t + 1) & 3][s * 32]);
            xq0 = xp[0];
            xq1 = xp[1];
            xq2 = xp[2];
            xq3 = xp[3];
        }

        // ---- gh partial dots (this lane's 16 of 32 j's) ----
        float gr = 0.f, gz = 0.f, gn = 0.f;
#pragma unroll
        for (int k = 0; k < 8; ++k) {
            gr = fdot2(ur2[k], hv2[k], gr);
            gz = fdot2(uz2[k], hv2[k], gz);
            gn = fdot2(un2[k], hv2[k], gn);
        }

        // ---- write my partials (one b128); partner read comes later ----
        float4 mypart;
        mypart.x = ar + gr;
        mypart.y = az + gz;
        mypart.z = an;
        mypart.w = gn;
        *reinterpret_cast<float4*>(&ps[s][h][0]) = mypart;
        __builtin_amdgcn_wave_barrier();

        // ---- staging for step t+3 (fills part of the round trip) ----
        xs16[(t + 3) & 3][lane] = (_Float16)ra;
        ra = rb; rb = rc;
        int tf = t + 6; if (tf > TS - 1) tf = TS - 1;   // harmless tail re-read
        rc = xrow[tf * DD + lane];

        // ---- xg partials for step t+1 (pure VALU on pre-read regs;
        //      issue time covers the ps round trip) ----
        if (t + 1 < TS) {
            half2v v0, v1, v2, v3;
            ar = 0.f; az = 0.f; an = 0.f;
            v0 = h2(xq0.x); v1 = h2(xq0.y); v2 = h2(xq0.z); v3 = h2(xq0.w);
            ar = fdot2(wr2[0], v0, ar);  az = fdot2(wz2[0], v0, az);  an = fdot2(wn2[0], v0, an);
            ar = fdot2(wr2[1], v1, ar);  az = fdot2(wz2[1], v1, az);  an = fdot2(wn2[1], v1, an);
            ar = fdot2(wr2[2], v2, ar);  az = fdot2(wz2[2], v2, az);  an = fdot2(wn2[2], v2, an);
            ar = fdot2(wr2[3], v3, ar);  az = fdot2(wz2[3], v3, az);  an = fdot2(wn2[3], v3, an);
            v0 = h2(xq1.x); v1 = h2(xq1.y); v2 = h2(xq1.z); v3 = h2(xq1.w);
            ar = fdot2(wr2[4], v0, ar);  az = fdot2(wz2[4], v0, az);  an = fdot2(wn2[4], v0, an);
            ar = fdot2(wr2[5], v1, ar);  az = fdot2(wz2[5], v1, az);  an = fdot2(wn2[5], v1, an);
            ar = fdot2(wr2[6], v2, ar);  az = fdot2(wz2[6], v2, az);  an = fdot2(wn2[6], v2, an);
            ar = fdot2(wr2[7], v3, ar);  az = fdot2(wz2[7], v3, az);  an = fdot2(wn2[7], v3, an);
            v0 = h2(xq2.x); v1 = h2(xq2.y); v2 = h2(xq2.z); v3 = h2(xq2.w);
            ar = fdot2(wr2[8], v0, ar);  az = fdot2(wz2[8], v0, az);  an = fdot2(wn2[8], v0, an);
            ar = fdot2(wr2[9], v1, ar);  az = fdot2(wz2[9], v1, az);  an = fdot2(wn2[9], v1, an);
            ar = fdot2(wr2[10], v2, ar); az = fdot2(wz2[10], v2, az); an = fdot2(wn2[10], v2, an);
            ar = fdot2(wr2[11], v3, ar); az = fdot2(wz2[11], v3, az); an = fdot2(wn2[11], v3, an);
            v0 = h2(xq3.x); v1 = h2(xq3.y); v2 = h2(xq3.z); v3 = h2(xq3.w);
            ar = fdot2(wr2[12], v0, ar); az = fdot2(wz2[12], v0, az); an = fdot2(wn2[12], v0, an);
            ar = fdot2(wr2[13], v1, ar); az = fdot2(wz2[13], v1, az); an = fdot2(wn2[13], v1, an);
            ar = fdot2(wr2[14], v2, ar); az = fdot2(wz2[14], v2, az); an = fdot2(wn2[14], v2, an);
            ar = fdot2(wr2[15], v3, ar); az = fdot2(wz2[15], v3, az); an = fdot2(wn2[15], v3, an);
        }

        // ---- read partner partials and combine ----
        __builtin_amdgcn_wave_barrier();
        float4 other = *reinterpret_cast<const float4*>(&ps[s ^ 1][h][0]);
        float tr  = mypart.x + other.x;   // scaled by log2e
        float tz  = mypart.y + other.y;   // scaled by log2e
        float txn = mypart.z + other.z;   // scaled by 2*log2e
        float tgn = mypart.w + other.w;   // scaled by 2*log2e

        // ---- gates: exp2-direct (log2e pre-folded into weights) ----
        float r = __builtin_amdgcn_rcpf(1.0f + fexp2(-(tr + br)));
        float z = __builtin_amdgcn_rcpf(1.0f + fexp2(-(tz + bz)));
        float npre2 = txn + bxn + r * (tgn + bhn);   // = 2*log2e*npre
        npre2 = fmaxf(npre2, -60.f);                 // only -inf side can NaN
        float e2 = fexp2(-npre2);
        float n = (1.f - e2) * __builtin_amdgcn_rcpf(1.f + e2);
        h_own = n + z * (h_own - n);

        // ---- broadcast h (fp16) — wave-synchronous, block == 1 wave ----
        hs16[h] = (_Float16)h_own;
        __builtin_amdgcn_wave_barrier();
        {
            const uint4* hp = reinterpret_cast<const uint4*>(&hs16[s * 16]);
            uint4 q0 = hp[0];
            uint4 q1 = hp[1];
            hv2[0] = h2(q0.x);
            hv2[1] = h2(q0.y);
            hv2[2] = h2(q0.z);
            hv2[3] = h2(q0.w);
            hv2[4] = h2(q1.x);
            hv2[5] = h2(q1.y);
            hv2[6] = h2(q1.z);
            hv2[7] = h2(q1.w);
        }
    }

    // ---- final fc: out[b] = dot(h, W_fc) + b_fc (each h counted twice) ----
    float v = h_own * wfc;
#pragma unroll
    for (int off = 32; off >= 1; off >>= 1) v += __shfl_xor(v, off);
    if (lane == 0) out[b] = 0.5f * v + bf0;
}

extern "C" void kernel_launch(void* const* d_in, const int* in_sizes, int n_in,
                              void* d_out, int out_size, void* d_ws, size_t ws_size,
                              hipStream_t stream) {
    const float* x    = (const float*)d_in[0];
    const float* Wih  = (const float*)d_in[1];
    const float* Whh  = (const float*)d_in[2];
    const float* bih  = (const float*)d_in[3];
    const float* bhh  = (const float*)d_in[4];
    const float* Wfc  = (const float*)d_in[5];
    const float* bfc  = (const float*)d_in[6];
    float* out = (float*)d_out;

    const int B = in_sizes[0] / (TS * DD);   // 1024
    gru_fused<<<dim3(B), dim3(64), 0, stream>>>(x, Wih, Whh, bih, bhh, Wfc, bfc, out);
}